// Round 10
// baseline (854.356 us; speedup 1.0000x reference)
//
#include <hip/hip_runtime.h>
#include <cstddef>
#include <cstdint>

typedef short short8 __attribute__((ext_vector_type(8)));
typedef float f32x4 __attribute__((ext_vector_type(4)));
typedef unsigned short ushort_t;
typedef unsigned int uint_t;
typedef ushort_t ushort4v __attribute__((ext_vector_type(4)));
typedef float f32x4v __attribute__((ext_vector_type(4)));

#define INV_LN2 1.4426950408889634f
#define RESCALE_THR 12.0f

__device__ __forceinline__ float bf16_to_f(ushort_t u) {
  union { unsigned int i; float f; } v; v.i = ((unsigned int)u) << 16; return v.f;
}
__device__ __forceinline__ float lo16f(uint_t u) {
  union { uint_t i; float f; } v; v.i = u << 16; return v.f;
}
__device__ __forceinline__ float hi16f(uint_t u) {
  union { uint_t i; float f; } v; v.i = u & 0xffff0000u; return v.f;
}
__device__ __forceinline__ ushort_t f_to_bf16(float f) {
  union { float ff; unsigned int i; } v; v.ff = f;
  unsigned int x = v.i;
  unsigned int lsb = (x >> 16) & 1u;
  x += 0x7fffu + lsb;
  return (ushort_t)(x >> 16);
}
__device__ __forceinline__ uint_t pack_hl(float f) {
  ushort_t hb = f_to_bf16(f);
  ushort_t lb = f_to_bf16(f - bf16_to_f(hb));
  return (uint_t)hb | ((uint_t)lb << 16);
}
__device__ __forceinline__ ushort_t f_to_f16(float f) {
  _Float16 h = (_Float16)f;
  union { _Float16 h; ushort_t u; } v; v.h = h; return v.u;
}
__device__ __forceinline__ float f16_to_f(ushort_t u) {
  union { ushort_t u; _Float16 h; } v; v.u = u; return (float)v.h;
}

// ---------------------------------------------------------------------------
// CSR build
// ---------------------------------------------------------------------------
__global__ __launch_bounds__(64) void detect_i64_kernel(const int* __restrict__ ei,
                                                        int* __restrict__ flag) {
  if (threadIdx.x == 0) {
    int is32 = 0;
    for (int i = 1; i < 1001; i += 2) {
      if (ei[i] != 0) { is32 = 1; break; }
    }
    *flag = is32;
  }
}

__device__ __forceinline__ int load_src(const int* ei, int is32, int E, int e) {
  return is32 ? ei[e] : ei[2 * e];
}
__device__ __forceinline__ int load_dst(const int* ei, int is32, int E, int e) {
  return is32 ? ei[E + e] : ei[2 * (E + e)];
}

__global__ __launch_bounds__(256) void deg_kernel(const int* __restrict__ ei,
                                                  const int* __restrict__ flag,
                                                  int E, int N, int* __restrict__ deg) {
  int e = blockIdx.x * 256 + threadIdx.x;
  if (e >= E + N) return;
  int d = (e < E) ? load_dst(ei, *flag, E, e) : (e - E);
  atomicAdd(&deg[d], 1);
}

__global__ __launch_bounds__(256) void scan_blk_kernel(const int* __restrict__ deg,
                                                       int* __restrict__ rowptr,
                                                       int* __restrict__ bsum, int N) {
  __shared__ int buf[256];
  int b = blockIdx.x, t = threadIdx.x, i = b * 256 + t;
  int v = (i < N) ? deg[i] : 0;
  buf[t] = v;
  __syncthreads();
  for (int off = 1; off < 256; off <<= 1) {
    int add = (t >= off) ? buf[t - off] : 0;
    __syncthreads();
    buf[t] += add;
    __syncthreads();
  }
  if (i < N) rowptr[i + 1] = buf[t];
  if (t == 255) bsum[b] = buf[255];
  if (b == 0 && t == 0) rowptr[0] = 0;
}

__global__ __launch_bounds__(256) void scan_top_kernel(int* __restrict__ bsum, int NB) {
  __shared__ int buf[256];
  int t = threadIdx.x;
  int v = (t < NB) ? bsum[t] : 0;
  buf[t] = v;
  __syncthreads();
  for (int off = 1; off < 256; off <<= 1) {
    int add = (t >= off) ? buf[t - off] : 0;
    __syncthreads();
    buf[t] += add;
    __syncthreads();
  }
  if (t < NB) bsum[t] = buf[t];
}

__global__ __launch_bounds__(256) void scan_add_kernel(int* __restrict__ rowptr,
                                                       const int* __restrict__ bsum, int N) {
  int b = blockIdx.x, t = threadIdx.x, i = b * 256 + t;
  if (b > 0 && i < N) rowptr[i + 1] += bsum[b - 1];
}

__global__ __launch_bounds__(256) void fill_kernel(const int* __restrict__ ei,
                                                   const int* __restrict__ flag,
                                                   int E, int N,
                                                   const int* __restrict__ rowptr,
                                                   int* __restrict__ fillc,
                                                   int* __restrict__ colbuf) {
  int e = blockIdx.x * 256 + threadIdx.x;
  if (e >= E + N) return;
  int s, d;
  if (e < E) { int is32 = *flag; s = load_src(ei, is32, E, e); d = load_dst(ei, is32, E, e); }
  else { s = e - E; d = s; }
  int pos = atomicAdd(&fillc[d], 1);
  colbuf[rowptr[d] + pos] = s;
}

// ---- degree sort: counting sort -> perm[row] = node (equal-degree pairing) --
__global__ __launch_bounds__(256) void hist_kernel(const int* __restrict__ deg,
                                                   int* __restrict__ hist, int N) {
  int n = blockIdx.x * 256 + threadIdx.x;
  if (n < N) atomicAdd(&hist[min(deg[n], 63)], 1);
}

__global__ __launch_bounds__(64) void binscan_kernel(const int* __restrict__ hist,
                                                     int* __restrict__ binoff) {
  if (threadIdx.x == 0) {
    int acc = 0;
    for (int i = 0; i < 64; ++i) { binoff[i] = acc; acc += hist[i]; }
  }
}

__global__ __launch_bounds__(256) void permfill_kernel(const int* __restrict__ deg,
                                                       const int* __restrict__ binoff,
                                                       int* __restrict__ cnt2,
                                                       int* __restrict__ perm,
                                                       int N, int Mp) {
  int n = blockIdx.x * 256 + threadIdx.x;
  if (n < N) {
    int b = min(deg[n], 63);
    int pos = binoff[b] + atomicAdd(&cnt2[b], 1);
    perm[pos] = n;
  } else if (n < Mp) {
    perm[n] = -1;
  }
}

// ---------------------------------------------------------------------------
// prep kernels
// ---------------------------------------------------------------------------
// fp32 -> packed (bf16hi|bf16lo) uint (for al) + fp16 ushort (for agg gather)
__global__ __launch_bounds__(256) void split_x_i_kernel(const float* __restrict__ h,
                                                        uint_t* __restrict__ hi,
                                                        ushort_t* __restrict__ h16,
                                                        int n) {
  int i = (blockIdx.x * 256 + threadIdx.x) * 4;
  if (i >= n) return;
  f32x4v v = *(const f32x4v*)&h[i];
  uint4 o;
  o.x = pack_hl(v[0]); o.y = pack_hl(v[1]); o.z = pack_hl(v[2]); o.w = pack_hl(v[3]);
  *(uint4*)&hi[i] = o;
  ushort4v s;
  s[0] = f_to_f16(v[0]); s[1] = f_to_f16(v[1]);
  s[2] = f_to_f16(v[2]); s[3] = f_to_f16(v[3]);
  *(ushort4v*)&h16[i] = s;
}

// Wp [k=128][col=128] fp32 -> frag layout hi/lo
__global__ __launch_bounds__(256) void split_wt_frag_kernel(const float* __restrict__ W,
                                                            ushort_t* __restrict__ hi,
                                                            ushort_t* __restrict__ lo) {
  int t = blockIdx.x * 256 + threadIdx.x;   // 16384
  int blk = t >> 7, rem = t & 127;
  int c16 = blk >> 4, k8 = blk & 15;
  int cl = rem >> 3, kl = rem & 7;
  int col = c16 * 16 + cl, k = k8 * 8 + kl;
  float f = W[(size_t)k * 128 + col];
  ushort_t hb = f_to_bf16(f);
  hi[t] = hb;
  lo[t] = f_to_bf16(f - bf16_to_f(hb));
}

// W [128][512] -> Wstack frag layout (K=512)
__global__ __launch_bounds__(256) void split_wstack_frag_kernel(const float* __restrict__ W,
                                                                ushort_t* __restrict__ hi,
                                                                ushort_t* __restrict__ lo) {
  int t = blockIdx.x * 256 + threadIdx.x;   // 65536
  int c16 = t >> 13;
  int r = t & 8191;
  int k8 = r >> 7;
  int rem = r & 127;
  int rl = rem >> 3, kl = rem & 7;
  int col = c16 * 16 + rl;
  int k = k8 * 8 + kl;
  int h = k >> 7, f = k & 127;
  float v = 0.25f * W[(size_t)f * 512 + h * 128 + col];
  ushort_t hb = f_to_bf16(v);
  hi[t] = hb;
  lo[t] = f_to_bf16(v - bf16_to_f(hb));
}

// Ws[h*128+f] = (1/ln2) * sum_d W[f, h*128+d] * a_src[h, d]
__global__ __launch_bounds__(256) void wsd_kernel(const float* __restrict__ W,
                                                  const float* __restrict__ a_src,
                                                  const float* __restrict__ a_dst,
                                                  float* __restrict__ Ws,
                                                  float* __restrict__ Wd) {
  int wave = threadIdx.x >> 6, lane = threadIdx.x & 63;
  int f = blockIdx.x * 4 + wave;          // grid = 32 -> f in [0,128)
  int base = lane * 8;
  float4 w0 = *(const float4*)&W[(size_t)f * 512 + base];
  float4 w1 = *(const float4*)&W[(size_t)f * 512 + base + 4];
  float4 s0 = *(const float4*)&a_src[base];
  float4 s1 = *(const float4*)&a_src[base + 4];
  float4 d0 = *(const float4*)&a_dst[base];
  float4 d1 = *(const float4*)&a_dst[base + 4];
  float ps = w0.x*s0.x + w0.y*s0.y + w0.z*s0.z + w0.w*s0.w
           + w1.x*s1.x + w1.y*s1.y + w1.z*s1.z + w1.w*s1.w;
  float pd = w0.x*d0.x + w0.y*d0.y + w0.z*d0.z + w0.w*d0.w
           + w1.x*d1.x + w1.y*d1.y + w1.z*d1.z + w1.w*d1.w;
#pragma unroll
  for (int off = 1; off <= 8; off <<= 1) {
    ps += __shfl_xor(ps, off);
    pd += __shfl_xor(pd, off);
  }
  if ((lane & 15) == 0) {
    int h = lane >> 4;
    Ws[h * 128 + f] = ps * INV_LN2;
    Wd[h * 128 + f] = pd * INV_LN2;
  }
}

// al_src/al_dst [N,4] from packed hi/lo h (full precision). One wave per node.
__global__ __launch_bounds__(256) void al_kernel_i(const uint_t* __restrict__ hint,
                                                   const float* __restrict__ Ws,
                                                   const float* __restrict__ Wd,
                                                   float* __restrict__ al_src,
                                                   float* __restrict__ al_dst, int N) {
  __shared__ float sWs[512], sWd[512];
  int t = threadIdx.x;
  sWs[t] = Ws[t]; sWs[t + 256] = Ws[t + 256];
  sWd[t] = Wd[t]; sWd[t + 256] = Wd[t + 256];
  __syncthreads();
  int wave = t >> 6, lane = t & 63;
  int n = blockIdx.x * 4 + wave;
  if (n >= N) return;
  uint2 uu = *(const uint2*)&hint[(size_t)n * 128 + lane * 2];
  float v0 = lo16f(uu.x) + hi16f(uu.x);
  float v1 = lo16f(uu.y) + hi16f(uu.y);
  float p[8];
#pragma unroll
  for (int hh = 0; hh < 4; ++hh) {
    p[hh]     = v0 * sWs[hh * 128 + 2 * lane] + v1 * sWs[hh * 128 + 2 * lane + 1];
    p[4 + hh] = v0 * sWd[hh * 128 + 2 * lane] + v1 * sWd[hh * 128 + 2 * lane + 1];
  }
#pragma unroll
  for (int off = 32; off; off >>= 1)
#pragma unroll
    for (int i = 0; i < 8; ++i) p[i] += __shfl_xor(p[i], off);
  if (lane == 0) {
#pragma unroll
    for (int hh = 0; hh < 4; ++hh) {
      al_src[n * 4 + hh] = p[hh];
      al_dst[n * 4 + hh] = p[4 + hh];
    }
  }
}

// ---------------------------------------------------------------------------
// aggregation: row r <-> node perm[r] (degree-sorted). 2 rows per wave.
// fp16 value gather (8 B/lane); exp2-domain online softmax, deferred rescale;
// 2-deep pipelined gathers; frag-layout output (zero rows for dead perm).
// ---------------------------------------------------------------------------
__global__ __launch_bounds__(256) void agg_G_kernel(const ushort_t* __restrict__ h16,
                                                    const float* __restrict__ al_src,
                                                    const float* __restrict__ al_dst,
                                                    const int* __restrict__ rowptr,
                                                    const int* __restrict__ colbuf,
                                                    const int* __restrict__ perm,
                                                    ushort_t* __restrict__ Ghi,
                                                    ushort_t* __restrict__ Glo) {
  int wave = threadIdx.x >> 6, lane = threadIdx.x & 63;
  int fl = lane & 31;
  int r = blockIdx.x * 8 + wave * 2 + (lane >> 5);
  int n = perm[r];
  bool alive = n >= 0;
  int beg = 0, d = 0;
  float4 ald = make_float4(0.f, 0.f, 0.f, 0.f);
  if (alive) {
    beg = rowptr[n];
    d = rowptr[n + 1] - beg;
    ald = *(const float4*)&al_dst[(size_t)n * 4];
  }
  int dmax = max(d, __shfl_xor(d, 32));
  int dm1 = max(d - 1, 0);
  float m0 = -1e30f, m1 = -1e30f, m2 = -1e30f, m3 = -1e30f;
  float t0 = -1e30f, t1 = -1e30f, t2 = -1e30f, t3 = -1e30f;
  float ss0 = 0.f, ss1 = 0.f, ss2 = 0.f, ss3 = 0.f;
  float a00 = 0.f, a01 = 0.f, a02 = 0.f, a03 = 0.f;
  float a10 = 0.f, a11 = 0.f, a12 = 0.f, a13 = 0.f;
  float a20 = 0.f, a21 = 0.f, a22 = 0.f, a23 = 0.f;
  float a30 = 0.f, a31 = 0.f, a32 = 0.f, a33 = 0.f;

  if (dmax > 0) {
    int s0i = colbuf[beg];
    float4 as_c = *(const float4*)&al_src[(size_t)s0i * 4];
    ushort4v hv_c = *(const ushort4v*)&h16[(size_t)s0i * 128 + fl * 4];
    int s_n = colbuf[beg + min(1, dm1)];
    for (int it = 0; it < dmax; ++it) {
      float4 as_n = *(const float4*)&al_src[(size_t)s_n * 4];
      ushort4v hv_n = *(const ushort4v*)&h16[(size_t)s_n * 128 + fl * 4];
      int s_n2 = colbuf[beg + min(it + 2, dm1)];

      float e0 = as_c.x + ald.x; e0 = fmaxf(e0, 0.2f * e0);
      float e1 = as_c.y + ald.y; e1 = fmaxf(e1, 0.2f * e1);
      float e2 = as_c.z + ald.z; e2 = fmaxf(e2, 0.2f * e2);
      float e3 = as_c.w + ald.w; e3 = fmaxf(e3, 0.2f * e3);
      bool need = (e0 > t0) || (e1 > t1) || (e2 > t2) || (e3 > t3);
      if (__any(need)) {
        float nm, f;
        nm = fmaxf(m0, e0); f = exp2f(m0 - nm); m0 = nm; t0 = nm + RESCALE_THR;
        ss0 *= f; a00 *= f; a01 *= f; a02 *= f; a03 *= f;
        nm = fmaxf(m1, e1); f = exp2f(m1 - nm); m1 = nm; t1 = nm + RESCALE_THR;
        ss1 *= f; a10 *= f; a11 *= f; a12 *= f; a13 *= f;
        nm = fmaxf(m2, e2); f = exp2f(m2 - nm); m2 = nm; t2 = nm + RESCALE_THR;
        ss2 *= f; a20 *= f; a21 *= f; a22 *= f; a23 *= f;
        nm = fmaxf(m3, e3); f = exp2f(m3 - nm); m3 = nm; t3 = nm + RESCALE_THR;
        ss3 *= f; a30 *= f; a31 *= f; a32 *= f; a33 *= f;
      }
      float w0 = exp2f(e0 - m0);
      float w1 = exp2f(e1 - m1);
      float w2 = exp2f(e2 - m2);
      float w3 = exp2f(e3 - m3);
      bool valid = it < d;
      w0 = valid ? w0 : 0.f;
      w1 = valid ? w1 : 0.f;
      w2 = valid ? w2 : 0.f;
      w3 = valid ? w3 : 0.f;
      ss0 += w0; ss1 += w1; ss2 += w2; ss3 += w3;
      float v0 = f16_to_f(hv_c[0]);
      float v1 = f16_to_f(hv_c[1]);
      float v2 = f16_to_f(hv_c[2]);
      float v3 = f16_to_f(hv_c[3]);
      a00 += w0 * v0; a01 += w0 * v1; a02 += w0 * v2; a03 += w0 * v3;
      a10 += w1 * v0; a11 += w1 * v1; a12 += w1 * v2; a13 += w1 * v3;
      a20 += w2 * v0; a21 += w2 * v1; a22 += w2 * v2; a23 += w2 * v3;
      a30 += w3 * v0; a31 += w3 * v1; a32 += w3 * v2; a33 += w3 * v3;
      as_c = as_n; hv_c = hv_n; s_n = s_n2;
    }
  }
  // dead rows: ss=0, acc=0 -> g=0 (writes zeros, keeps GEMM input clean)
  float g[4][4];
  float inv;
  inv = 1.f / (ss0 + 1e-16f); g[0][0] = a00 * inv; g[0][1] = a01 * inv; g[0][2] = a02 * inv; g[0][3] = a03 * inv;
  inv = 1.f / (ss1 + 1e-16f); g[1][0] = a10 * inv; g[1][1] = a11 * inv; g[1][2] = a12 * inv; g[1][3] = a13 * inv;
  inv = 1.f / (ss2 + 1e-16f); g[2][0] = a20 * inv; g[2][1] = a21 * inv; g[2][2] = a22 * inv; g[2][3] = a23 * inv;
  inv = 1.f / (ss3 + 1e-16f); g[3][0] = a30 * inv; g[3][1] = a31 * inv; g[3][2] = a32 * inv; g[3][3] = a33 * inv;
#pragma unroll
  for (int h = 0; h < 4; ++h) {
    ushort_t h0 = f_to_bf16(g[h][0]), h1 = f_to_bf16(g[h][1]);
    ushort_t h2 = f_to_bf16(g[h][2]), h3 = f_to_bf16(g[h][3]);
    ushort_t l0 = f_to_bf16(g[h][0] - bf16_to_f(h0)), l1 = f_to_bf16(g[h][1] - bf16_to_f(h1));
    ushort_t l2 = f_to_bf16(g[h][2] - bf16_to_f(h2)), l3 = f_to_bf16(g[h][3] - bf16_to_f(h3));
    size_t o = ((size_t)(r >> 4) * 64 + h * 16 + (fl >> 1)) * 128 + (r & 15) * 8 + (fl & 1) * 4;
    *(uint2*)&Ghi[o] = make_uint2((uint_t)h0 | ((uint_t)h1 << 16),
                                  (uint_t)h2 | ((uint_t)h3 << 16));
    *(uint2*)&Glo[o] = make_uint2((uint_t)l0 | ((uint_t)l1 << 16),
                                  (uint_t)l2 | ((uint_t)l3 << 16));
  }
}

// ---------------------------------------------------------------------------
// Barrier-free MFMA GEMM from fragment-layout inputs. Compile-time K/MODE.
// 4 waves/block, 16 rows/wave. Rows map to nodes via perm (scatter epilogue).
// MODE 0: packed-uint + fp16 row out (relu); 1: hi/lo frag out (relu);
// MODE 2: fp32 row out (no relu).
// ---------------------------------------------------------------------------
template <int K, int MODE>
__global__ __launch_bounds__(256) void gemm_frag_kernel(
    const ushort_t* __restrict__ Ahi, const ushort_t* __restrict__ Alo,
    const ushort_t* __restrict__ Bhi, const ushort_t* __restrict__ Blo,
    const int* __restrict__ perm,
    uint_t* __restrict__ Ci, ushort_t* __restrict__ H16,
    ushort_t* __restrict__ Chi, ushort_t* __restrict__ Clo,
    float* __restrict__ Cf, const float* __restrict__ bias) {
  constexpr int KT = K >> 5;
  constexpr int PS = 16 * K;          // panel stride (ushorts)
  int lane = threadIdx.x & 63;
  int wid = blockIdx.x * 4 + (threadIdx.x >> 6);
  int krow = lane >> 4, ml = lane & 15;
  int lb = krow * 128 + ml * 8;
  size_t abase = (size_t)wid * PS + lb;
  f32x4 acc[8] = {};
  short8 ah_c = *(const short8*)&Ahi[abase];
  short8 al_c = *(const short8*)&Alo[abase];
#pragma unroll
  for (int kt = 0; kt < KT; ++kt) {
    short8 ah_n = ah_c, al_n = al_c;
    if (kt + 1 < KT) {
      ah_n = *(const short8*)&Ahi[abase + (kt + 1) * 512];
      al_n = *(const short8*)&Alo[abase + (kt + 1) * 512];
    }
    short8 bh[8], bl[8];
#pragma unroll
    for (int j = 0; j < 8; ++j) {
      bh[j] = *(const short8*)&Bhi[j * PS + kt * 512 + lb];
      bl[j] = *(const short8*)&Blo[j * PS + kt * 512 + lb];
    }
#pragma unroll
    for (int j = 0; j < 8; ++j) {
      acc[j] = __builtin_amdgcn_mfma_f32_16x16x32_bf16(ah_c, bh[j], acc[j], 0, 0, 0);
      acc[j] = __builtin_amdgcn_mfma_f32_16x16x32_bf16(ah_c, bl[j], acc[j], 0, 0, 0);
      acc[j] = __builtin_amdgcn_mfma_f32_16x16x32_bf16(al_c, bh[j], acc[j], 0, 0, 0);
    }
    ah_c = ah_n; al_c = al_n;
  }
  int wrow0 = wid * 16;
  int prm[4];
#pragma unroll
  for (int r = 0; r < 4; ++r) prm[r] = perm[wrow0 + krow * 4 + r];
#pragma unroll
  for (int j = 0; j < 8; ++j) {
    int col = j * 16 + ml;
    float bv = bias[col];
#pragma unroll
    for (int r = 0; r < 4; ++r) {
      float v = acc[j][r] + bv;
      if (MODE != 2) v = fmaxf(v, 0.f);
      if (MODE == 0) {
        int node = prm[r];
        if (node >= 0) {
          Ci[(size_t)node * 128 + col] = pack_hl(v);
          H16[(size_t)node * 128 + col] = f_to_f16(v);
        }
      } else if (MODE == 1) {
        if (prm[r] >= 0) {
          int row = wrow0 + krow * 4 + r;
          size_t o = ((size_t)(row >> 4) * 16 + (col >> 3)) * 128 + (row & 15) * 8 + (col & 7);
          ushort_t hb = f_to_bf16(v);
          Chi[o] = hb;
          Clo[o] = f_to_bf16(v - bf16_to_f(hb));
        }
      } else {
        int node = prm[r];
        if (node >= 0) Cf[(size_t)node * 128 + col] = v;
      }
    }
  }
}

// ---------------------------------------------------------------------------
extern "C" void kernel_launch(void* const* d_in, const int* in_sizes, int n_in,
                              void* d_out, int out_size, void* d_ws, size_t ws_size,
                              hipStream_t stream) {
  const float* x  = (const float*)d_in[0];
  const int*   ei = (const int*)d_in[1];
  const float* Wl[3]  = {(const float*)d_in[2], (const float*)d_in[6], (const float*)d_in[10]};
  const float* asr[3] = {(const float*)d_in[3], (const float*)d_in[7], (const float*)d_in[11]};
  const float* adr[3] = {(const float*)d_in[4], (const float*)d_in[8], (const float*)d_in[12]};
  const float* bl[3]  = {(const float*)d_in[5], (const float*)d_in[9], (const float*)d_in[13]};
  const float* Wp = (const float*)d_in[14];
  const float* bp = (const float*)d_in[15];

  const int N = in_sizes[0] / 128;   // 50000
  const int E = in_sizes[1] / 2;     // 400000
  const int EN = E + N;
  const int Mtiles = (N + 127) / 128;  // 391
  const int Mp = Mtiles * 128;         // 50048
  const int NB = (N + 255) / 256;
  const int NPB = Mp / 16 / 4;         // 782 GEMM blocks

  char* ws = (char*)d_ws;
  size_t off = 0;
  auto carve = [&](size_t bytes) -> void* {
    void* p = ws + off;
    off = (off + bytes + 255) & ~(size_t)255;
    return p;
  };
  ushort_t* Ghi   = (ushort_t*)carve((size_t)Mp * 512 * 2);  // frag layout
  ushort_t* Glo   = (ushort_t*)carve((size_t)Mp * 512 * 2);
  uint_t*   hiA   = (uint_t*)carve((size_t)N * 128 * 4);     // packed hi/lo (al)
  uint_t*   hiB   = (uint_t*)carve((size_t)N * 128 * 4);
  ushort_t* h16   = (ushort_t*)carve((size_t)N * 128 * 2);   // fp16 (agg gather)
  ushort_t* h3hi  = (ushort_t*)carve((size_t)Mp * 128 * 2);  // frag (proj input)
  ushort_t* h3lo  = (ushort_t*)carve((size_t)Mp * 128 * 2);
  ushort_t* wshi  = (ushort_t*)carve((size_t)128 * 512 * 2);
  ushort_t* wslo  = (ushort_t*)carve((size_t)128 * 512 * 2);
  float*    alsrc = (float*)carve((size_t)N * 4 * 4);
  float*    aldst = (float*)carve((size_t)N * 4 * 4);
  float*    Wsb   = (float*)carve(512 * 4);
  float*    Wdb   = (float*)carve(512 * 4);
  int*      rowptr= (int*)carve((size_t)(N + 1) * 4);
  int*      deg   = (int*)carve((size_t)N * 4);
  int*      bsum  = (int*)carve(256 * 4);
  int*      fillc = (int*)carve((size_t)N * 4);
  int*      colbuf= (int*)carve((size_t)EN * 4);
  int*      perm  = (int*)carve((size_t)Mp * 4);
  int*      hist  = (int*)carve(64 * 4);
  int*      binoff= (int*)carve(64 * 4);
  int*      cnt2  = (int*)carve(64 * 4);
  int*      flag  = (int*)carve(256);

  // ---- CSR build + degree sort ----
  detect_i64_kernel<<<1, 64, 0, stream>>>(ei, flag);
  hipMemsetAsync(deg, 0, (size_t)N * 4, stream);
  hipMemsetAsync(fillc, 0, (size_t)N * 4, stream);
  hipMemsetAsync(hist, 0, 64 * 4, stream);
  hipMemsetAsync(cnt2, 0, 64 * 4, stream);
  int ebl = (EN + 255) / 256;
  deg_kernel<<<ebl, 256, 0, stream>>>(ei, flag, E, N, deg);
  scan_blk_kernel<<<NB, 256, 0, stream>>>(deg, rowptr, bsum, N);
  scan_top_kernel<<<1, 256, 0, stream>>>(bsum, NB);
  scan_add_kernel<<<NB, 256, 0, stream>>>(rowptr, bsum, N);
  fill_kernel<<<ebl, 256, 0, stream>>>(ei, flag, E, N, rowptr, fillc, colbuf);
  hist_kernel<<<NB, 256, 0, stream>>>(deg, hist, N);
  binscan_kernel<<<1, 64, 0, stream>>>(hist, binoff);
  permfill_kernel<<<(Mp + 255) / 256, 256, 0, stream>>>(deg, binoff, cnt2, perm, N, Mp);

  // ---- split x into packed + fp16 ----
  const int n_real = N * 128;
  split_x_i_kernel<<<(n_real / 4 + 255) / 256, 256, 0, stream>>>(x, hiA, h16, n_real);

  // ---- 3 GAT layers ----
  uint_t* hin = hiA;
  uint_t* hnext = hiB;
  for (int L = 0; L < 3; ++L) {
    wsd_kernel<<<32, 256, 0, stream>>>(Wl[L], asr[L], adr[L], Wsb, Wdb);
    al_kernel_i<<<(N + 3) / 4, 256, 0, stream>>>(hin, Wsb, Wdb, alsrc, aldst, N);
    agg_G_kernel<<<Mp / 8, 256, 0, stream>>>(h16, alsrc, aldst,
                                             rowptr, colbuf, perm, Ghi, Glo);
    split_wstack_frag_kernel<<<256, 256, 0, stream>>>(Wl[L], wshi, wslo);
    if (L < 2) {
      gemm_frag_kernel<512, 0><<<NPB, 256, 0, stream>>>(Ghi, Glo, wshi, wslo, perm,
                                                        hnext, h16, nullptr, nullptr,
                                                        nullptr, bl[L]);
      uint_t* t = hin; hin = hnext; hnext = t;
    } else {
      gemm_frag_kernel<512, 1><<<NPB, 256, 0, stream>>>(Ghi, Glo, wshi, wslo, perm,
                                                        nullptr, nullptr, h3hi, h3lo,
                                                        nullptr, bl[L]);
    }
  }

  // ---- final projection: out = h3 @ Wp + bp ----
  split_wt_frag_kernel<<<64, 256, 0, stream>>>(Wp, wshi, wslo);
  gemm_frag_kernel<128, 2><<<NPB, 256, 0, stream>>>(h3hi, h3lo, wshi, wslo, perm,
                                                    nullptr, nullptr, nullptr, nullptr,
                                                    (float*)d_out, bp);
}

// Round 11
// 481.610 us; speedup vs baseline: 1.7740x; 1.7740x over previous
//
#include <hip/hip_runtime.h>
#include <cstddef>
#include <cstdint>

typedef short short8 __attribute__((ext_vector_type(8)));
typedef float f32x4 __attribute__((ext_vector_type(4)));
typedef unsigned short ushort_t;
typedef unsigned int uint_t;
typedef ushort_t ushort4v __attribute__((ext_vector_type(4)));
typedef float f32x4v __attribute__((ext_vector_type(4)));

#define INV_LN2 1.4426950408889634f
#define RESCALE_THR 12.0f

__device__ __forceinline__ float bf16_to_f(ushort_t u) {
  union { unsigned int i; float f; } v; v.i = ((unsigned int)u) << 16; return v.f;
}
__device__ __forceinline__ float lo16f(uint_t u) {
  union { uint_t i; float f; } v; v.i = u << 16; return v.f;
}
__device__ __forceinline__ float hi16f(uint_t u) {
  union { uint_t i; float f; } v; v.i = u & 0xffff0000u; return v.f;
}
__device__ __forceinline__ ushort_t f_to_bf16(float f) {
  union { float ff; unsigned int i; } v; v.ff = f;
  unsigned int x = v.i;
  unsigned int lsb = (x >> 16) & 1u;
  x += 0x7fffu + lsb;
  return (ushort_t)(x >> 16);
}
__device__ __forceinline__ uint_t pack_hl(float f) {
  ushort_t hb = f_to_bf16(f);
  ushort_t lb = f_to_bf16(f - bf16_to_f(hb));
  return (uint_t)hb | ((uint_t)lb << 16);
}
__device__ __forceinline__ ushort_t f_to_f16(float f) {
  _Float16 h = (_Float16)f;
  union { _Float16 h; ushort_t u; } v; v.h = h; return v.u;
}
__device__ __forceinline__ float f16_to_f(ushort_t u) {
  union { ushort_t u; _Float16 h; } v; v.u = u; return (float)v.h;
}

// ---------------------------------------------------------------------------
// CSR build
// ---------------------------------------------------------------------------
__global__ __launch_bounds__(64) void detect_i64_kernel(const int* __restrict__ ei,
                                                        int* __restrict__ flag) {
  if (threadIdx.x == 0) {
    int is32 = 0;
    for (int i = 1; i < 1001; i += 2) {
      if (ei[i] != 0) { is32 = 1; break; }
    }
    *flag = is32;
  }
}

__device__ __forceinline__ int load_src(const int* ei, int is32, int E, int e) {
  return is32 ? ei[e] : ei[2 * e];
}
__device__ __forceinline__ int load_dst(const int* ei, int is32, int E, int e) {
  return is32 ? ei[E + e] : ei[2 * (E + e)];
}

__global__ __launch_bounds__(256) void deg_kernel(const int* __restrict__ ei,
                                                  const int* __restrict__ flag,
                                                  int E, int N, int* __restrict__ deg) {
  int e = blockIdx.x * 256 + threadIdx.x;
  if (e >= E + N) return;
  int d = (e < E) ? load_dst(ei, *flag, E, e) : (e - E);
  atomicAdd(&deg[d], 1);
}

__global__ __launch_bounds__(256) void scan_blk_kernel(const int* __restrict__ deg,
                                                       int* __restrict__ rowptr,
                                                       int* __restrict__ bsum, int N) {
  __shared__ int buf[256];
  int b = blockIdx.x, t = threadIdx.x, i = b * 256 + t;
  int v = (i < N) ? deg[i] : 0;
  buf[t] = v;
  __syncthreads();
  for (int off = 1; off < 256; off <<= 1) {
    int add = (t >= off) ? buf[t - off] : 0;
    __syncthreads();
    buf[t] += add;
    __syncthreads();
  }
  if (i < N) rowptr[i + 1] = buf[t];
  if (t == 255) bsum[b] = buf[255];
  if (b == 0 && t == 0) rowptr[0] = 0;
}

__global__ __launch_bounds__(256) void scan_top_kernel(int* __restrict__ bsum, int NB) {
  __shared__ int buf[256];
  int t = threadIdx.x;
  int v = (t < NB) ? bsum[t] : 0;
  buf[t] = v;
  __syncthreads();
  for (int off = 1; off < 256; off <<= 1) {
    int add = (t >= off) ? buf[t - off] : 0;
    __syncthreads();
    buf[t] += add;
    __syncthreads();
  }
  if (t < NB) bsum[t] = buf[t];
}

__global__ __launch_bounds__(256) void scan_add_kernel(int* __restrict__ rowptr,
                                                       const int* __restrict__ bsum, int N) {
  int b = blockIdx.x, t = threadIdx.x, i = b * 256 + t;
  if (b > 0 && i < N) rowptr[i + 1] += bsum[b - 1];
}

__global__ __launch_bounds__(256) void fill_kernel(const int* __restrict__ ei,
                                                   const int* __restrict__ flag,
                                                   int E, int N,
                                                   const int* __restrict__ rowptr,
                                                   int* __restrict__ fillc,
                                                   int* __restrict__ colbuf) {
  int e = blockIdx.x * 256 + threadIdx.x;
  if (e >= E + N) return;
  int s, d;
  if (e < E) { int is32 = *flag; s = load_src(ei, is32, E, e); d = load_dst(ei, is32, E, e); }
  else { s = e - E; d = s; }
  int pos = atomicAdd(&fillc[d], 1);
  colbuf[rowptr[d] + pos] = s;
}

// ---------------------------------------------------------------------------
// prep kernels
// ---------------------------------------------------------------------------
// fp32 -> packed (bf16hi|bf16lo) uint (for al) + fp16 ushort (for agg gather)
__global__ __launch_bounds__(256) void split_x_i_kernel(const float* __restrict__ h,
                                                        uint_t* __restrict__ hi,
                                                        ushort_t* __restrict__ h16,
                                                        int n) {
  int i = (blockIdx.x * 256 + threadIdx.x) * 4;
  if (i >= n) return;
  f32x4v v = *(const f32x4v*)&h[i];
  uint4 o;
  o.x = pack_hl(v[0]); o.y = pack_hl(v[1]); o.z = pack_hl(v[2]); o.w = pack_hl(v[3]);
  *(uint4*)&hi[i] = o;
  ushort4v s;
  s[0] = f_to_f16(v[0]); s[1] = f_to_f16(v[1]);
  s[2] = f_to_f16(v[2]); s[3] = f_to_f16(v[3]);
  *(ushort4v*)&h16[i] = s;
}

// Wp [k=128][col=128] fp32 -> frag layout hi/lo
__global__ __launch_bounds__(256) void split_wt_frag_kernel(const float* __restrict__ W,
                                                            ushort_t* __restrict__ hi,
                                                            ushort_t* __restrict__ lo) {
  int t = blockIdx.x * 256 + threadIdx.x;   // 16384
  int blk = t >> 7, rem = t & 127;
  int c16 = blk >> 4, k8 = blk & 15;
  int cl = rem >> 3, kl = rem & 7;
  int col = c16 * 16 + cl, k = k8 * 8 + kl;
  float f = W[(size_t)k * 128 + col];
  ushort_t hb = f_to_bf16(f);
  hi[t] = hb;
  lo[t] = f_to_bf16(f - bf16_to_f(hb));
}

// W [128][512] -> Wstack frag layout (K=512)
__global__ __launch_bounds__(256) void split_wstack_frag_kernel(const float* __restrict__ W,
                                                                ushort_t* __restrict__ hi,
                                                                ushort_t* __restrict__ lo) {
  int t = blockIdx.x * 256 + threadIdx.x;   // 65536
  int c16 = t >> 13;
  int r = t & 8191;
  int k8 = r >> 7;
  int rem = r & 127;
  int rl = rem >> 3, kl = rem & 7;
  int col = c16 * 16 + rl;
  int k = k8 * 8 + kl;
  int h = k >> 7, f = k & 127;
  float v = 0.25f * W[(size_t)f * 512 + h * 128 + col];
  ushort_t hb = f_to_bf16(v);
  hi[t] = hb;
  lo[t] = f_to_bf16(v - bf16_to_f(hb));
}

// Ws[h*128+f] = (1/ln2) * sum_d W[f, h*128+d] * a_src[h, d]
__global__ __launch_bounds__(256) void wsd_kernel(const float* __restrict__ W,
                                                  const float* __restrict__ a_src,
                                                  const float* __restrict__ a_dst,
                                                  float* __restrict__ Ws,
                                                  float* __restrict__ Wd) {
  int wave = threadIdx.x >> 6, lane = threadIdx.x & 63;
  int f = blockIdx.x * 4 + wave;          // grid = 32 -> f in [0,128)
  int base = lane * 8;
  float4 w0 = *(const float4*)&W[(size_t)f * 512 + base];
  float4 w1 = *(const float4*)&W[(size_t)f * 512 + base + 4];
  float4 s0 = *(const float4*)&a_src[base];
  float4 s1 = *(const float4*)&a_src[base + 4];
  float4 d0 = *(const float4*)&a_dst[base];
  float4 d1 = *(const float4*)&a_dst[base + 4];
  float ps = w0.x*s0.x + w0.y*s0.y + w0.z*s0.z + w0.w*s0.w
           + w1.x*s1.x + w1.y*s1.y + w1.z*s1.z + w1.w*s1.w;
  float pd = w0.x*d0.x + w0.y*d0.y + w0.z*d0.z + w0.w*d0.w
           + w1.x*d1.x + w1.y*d1.y + w1.z*d1.z + w1.w*d1.w;
#pragma unroll
  for (int off = 1; off <= 8; off <<= 1) {
    ps += __shfl_xor(ps, off);
    pd += __shfl_xor(pd, off);
  }
  if ((lane & 15) == 0) {
    int h = lane >> 4;
    Ws[h * 128 + f] = ps * INV_LN2;
    Wd[h * 128 + f] = pd * INV_LN2;
  }
}

// al_src/al_dst [N,4] from packed hi/lo h (full precision). One wave per node.
__global__ __launch_bounds__(256) void al_kernel_i(const uint_t* __restrict__ hint,
                                                   const float* __restrict__ Ws,
                                                   const float* __restrict__ Wd,
                                                   float* __restrict__ al_src,
                                                   float* __restrict__ al_dst, int N) {
  __shared__ float sWs[512], sWd[512];
  int t = threadIdx.x;
  sWs[t] = Ws[t]; sWs[t + 256] = Ws[t + 256];
  sWd[t] = Wd[t]; sWd[t + 256] = Wd[t + 256];
  __syncthreads();
  int wave = t >> 6, lane = t & 63;
  int n = blockIdx.x * 4 + wave;
  if (n >= N) return;
  uint2 uu = *(const uint2*)&hint[(size_t)n * 128 + lane * 2];
  float v0 = lo16f(uu.x) + hi16f(uu.x);
  float v1 = lo16f(uu.y) + hi16f(uu.y);
  float p[8];
#pragma unroll
  for (int hh = 0; hh < 4; ++hh) {
    p[hh]     = v0 * sWs[hh * 128 + 2 * lane] + v1 * sWs[hh * 128 + 2 * lane + 1];
    p[4 + hh] = v0 * sWd[hh * 128 + 2 * lane] + v1 * sWd[hh * 128 + 2 * lane + 1];
  }
#pragma unroll
  for (int off = 32; off; off >>= 1)
#pragma unroll
    for (int i = 0; i < 8; ++i) p[i] += __shfl_xor(p[i], off);
  if (lane == 0) {
#pragma unroll
    for (int hh = 0; hh < 4; ++hh) {
      al_src[n * 4 + hh] = p[hh];
      al_dst[n * 4 + hh] = p[4 + hh];
    }
  }
}

// ---------------------------------------------------------------------------
// aggregation: 2 nodes per wave (32-lane halves); fp16 value gather (8 B/lane);
// exp2-domain online softmax with deferred rescale; 2-deep pipelined gathers;
// frag-layout output.
// ---------------------------------------------------------------------------
__global__ __launch_bounds__(256) void agg_G_kernel(const ushort_t* __restrict__ h16,
                                                    const float* __restrict__ al_src,
                                                    const float* __restrict__ al_dst,
                                                    const int* __restrict__ rowptr,
                                                    const int* __restrict__ colbuf,
                                                    ushort_t* __restrict__ Ghi,
                                                    ushort_t* __restrict__ Glo, int N) {
  int wave = threadIdx.x >> 6, lane = threadIdx.x & 63;
  int fl = lane & 31;
  int n = blockIdx.x * 8 + wave * 2 + (lane >> 5);
  bool alive = n < N;
  int beg = 0, d = 0;
  float4 ald = make_float4(0.f, 0.f, 0.f, 0.f);
  if (alive) {
    beg = rowptr[n];
    d = rowptr[n + 1] - beg;
    ald = *(const float4*)&al_dst[(size_t)n * 4];
  }
  int dmax = max(d, __shfl_xor(d, 32));
  int dm1 = max(d - 1, 0);
  float m0 = -1e30f, m1 = -1e30f, m2 = -1e30f, m3 = -1e30f;
  float t0 = -1e30f, t1 = -1e30f, t2 = -1e30f, t3 = -1e30f;
  float ss0 = 0.f, ss1 = 0.f, ss2 = 0.f, ss3 = 0.f;
  float a00 = 0.f, a01 = 0.f, a02 = 0.f, a03 = 0.f;
  float a10 = 0.f, a11 = 0.f, a12 = 0.f, a13 = 0.f;
  float a20 = 0.f, a21 = 0.f, a22 = 0.f, a23 = 0.f;
  float a30 = 0.f, a31 = 0.f, a32 = 0.f, a33 = 0.f;

  if (dmax > 0) {
    int s0i = colbuf[beg];
    float4 as_c = *(const float4*)&al_src[(size_t)s0i * 4];
    ushort4v hv_c = *(const ushort4v*)&h16[(size_t)s0i * 128 + fl * 4];
    int s_n = colbuf[beg + min(1, dm1)];
    for (int it = 0; it < dmax; ++it) {
      float4 as_n = *(const float4*)&al_src[(size_t)s_n * 4];
      ushort4v hv_n = *(const ushort4v*)&h16[(size_t)s_n * 128 + fl * 4];
      int s_n2 = colbuf[beg + min(it + 2, dm1)];

      float e0 = as_c.x + ald.x; e0 = fmaxf(e0, 0.2f * e0);
      float e1 = as_c.y + ald.y; e1 = fmaxf(e1, 0.2f * e1);
      float e2 = as_c.z + ald.z; e2 = fmaxf(e2, 0.2f * e2);
      float e3 = as_c.w + ald.w; e3 = fmaxf(e3, 0.2f * e3);
      bool need = (e0 > t0) || (e1 > t1) || (e2 > t2) || (e3 > t3);
      if (__any(need)) {
        float nm, f;
        nm = fmaxf(m0, e0); f = exp2f(m0 - nm); m0 = nm; t0 = nm + RESCALE_THR;
        ss0 *= f; a00 *= f; a01 *= f; a02 *= f; a03 *= f;
        nm = fmaxf(m1, e1); f = exp2f(m1 - nm); m1 = nm; t1 = nm + RESCALE_THR;
        ss1 *= f; a10 *= f; a11 *= f; a12 *= f; a13 *= f;
        nm = fmaxf(m2, e2); f = exp2f(m2 - nm); m2 = nm; t2 = nm + RESCALE_THR;
        ss2 *= f; a20 *= f; a21 *= f; a22 *= f; a23 *= f;
        nm = fmaxf(m3, e3); f = exp2f(m3 - nm); m3 = nm; t3 = nm + RESCALE_THR;
        ss3 *= f; a30 *= f; a31 *= f; a32 *= f; a33 *= f;
      }
      float w0 = exp2f(e0 - m0);
      float w1 = exp2f(e1 - m1);
      float w2 = exp2f(e2 - m2);
      float w3 = exp2f(e3 - m3);
      bool valid = it < d;
      w0 = valid ? w0 : 0.f;
      w1 = valid ? w1 : 0.f;
      w2 = valid ? w2 : 0.f;
      w3 = valid ? w3 : 0.f;
      ss0 += w0; ss1 += w1; ss2 += w2; ss3 += w3;
      float v0 = f16_to_f(hv_c[0]);
      float v1 = f16_to_f(hv_c[1]);
      float v2 = f16_to_f(hv_c[2]);
      float v3 = f16_to_f(hv_c[3]);
      a00 += w0 * v0; a01 += w0 * v1; a02 += w0 * v2; a03 += w0 * v3;
      a10 += w1 * v0; a11 += w1 * v1; a12 += w1 * v2; a13 += w1 * v3;
      a20 += w2 * v0; a21 += w2 * v1; a22 += w2 * v2; a23 += w2 * v3;
      a30 += w3 * v0; a31 += w3 * v1; a32 += w3 * v2; a33 += w3 * v3;
      as_c = as_n; hv_c = hv_n; s_n = s_n2;
    }
  }
  if (!alive) return;
  float g[4][4];
  float inv;
  inv = 1.f / (ss0 + 1e-16f); g[0][0] = a00 * inv; g[0][1] = a01 * inv; g[0][2] = a02 * inv; g[0][3] = a03 * inv;
  inv = 1.f / (ss1 + 1e-16f); g[1][0] = a10 * inv; g[1][1] = a11 * inv; g[1][2] = a12 * inv; g[1][3] = a13 * inv;
  inv = 1.f / (ss2 + 1e-16f); g[2][0] = a20 * inv; g[2][1] = a21 * inv; g[2][2] = a22 * inv; g[2][3] = a23 * inv;
  inv = 1.f / (ss3 + 1e-16f); g[3][0] = a30 * inv; g[3][1] = a31 * inv; g[3][2] = a32 * inv; g[3][3] = a33 * inv;
#pragma unroll
  for (int h = 0; h < 4; ++h) {
    ushort_t h0 = f_to_bf16(g[h][0]), h1 = f_to_bf16(g[h][1]);
    ushort_t h2 = f_to_bf16(g[h][2]), h3 = f_to_bf16(g[h][3]);
    ushort_t l0 = f_to_bf16(g[h][0] - bf16_to_f(h0)), l1 = f_to_bf16(g[h][1] - bf16_to_f(h1));
    ushort_t l2 = f_to_bf16(g[h][2] - bf16_to_f(h2)), l3 = f_to_bf16(g[h][3] - bf16_to_f(h3));
    size_t o = ((size_t)(n >> 4) * 64 + h * 16 + (fl >> 1)) * 128 + (n & 15) * 8 + (fl & 1) * 4;
    *(uint2*)&Ghi[o] = make_uint2((uint_t)h0 | ((uint_t)h1 << 16),
                                  (uint_t)h2 | ((uint_t)h3 << 16));
    *(uint2*)&Glo[o] = make_uint2((uint_t)l0 | ((uint_t)l1 << 16),
                                  (uint_t)l2 | ((uint_t)l3 << 16));
  }
}

// ---------------------------------------------------------------------------
// Barrier-free MFMA GEMM from fragment-layout inputs. Compile-time K/MODE.
// 4 waves/block, 16 rows/wave, coalesced row epilogues (identity mapping).
// MODE 0: packed-uint + fp16 row out (relu); 1: hi/lo frag out (relu);
// MODE 2: fp32 row out (no relu).
// ---------------------------------------------------------------------------
template <int K, int MODE>
__global__ __launch_bounds__(256) void gemm_frag_kernel(
    const ushort_t* __restrict__ Ahi, const ushort_t* __restrict__ Alo,
    const ushort_t* __restrict__ Bhi, const ushort_t* __restrict__ Blo,
    uint_t* __restrict__ Ci, ushort_t* __restrict__ H16,
    ushort_t* __restrict__ Chi, ushort_t* __restrict__ Clo,
    float* __restrict__ Cf, int M, const float* __restrict__ bias) {
  constexpr int KT = K >> 5;
  constexpr int PS = 16 * K;          // panel stride (ushorts)
  int lane = threadIdx.x & 63;
  int wid = blockIdx.x * 4 + (threadIdx.x >> 6);
  int krow = lane >> 4, ml = lane & 15;
  int lb = krow * 128 + ml * 8;
  size_t abase = (size_t)wid * PS + lb;
  f32x4 acc[8] = {};
  short8 ah_c = *(const short8*)&Ahi[abase];
  short8 al_c = *(const short8*)&Alo[abase];
#pragma unroll
  for (int kt = 0; kt < KT; ++kt) {
    short8 ah_n = ah_c, al_n = al_c;
    if (kt + 1 < KT) {
      ah_n = *(const short8*)&Ahi[abase + (kt + 1) * 512];
      al_n = *(const short8*)&Alo[abase + (kt + 1) * 512];
    }
    short8 bh[8], bl[8];
#pragma unroll
    for (int j = 0; j < 8; ++j) {
      bh[j] = *(const short8*)&Bhi[j * PS + kt * 512 + lb];
      bl[j] = *(const short8*)&Blo[j * PS + kt * 512 + lb];
    }
#pragma unroll
    for (int j = 0; j < 8; ++j) {
      acc[j] = __builtin_amdgcn_mfma_f32_16x16x32_bf16(ah_c, bh[j], acc[j], 0, 0, 0);
      acc[j] = __builtin_amdgcn_mfma_f32_16x16x32_bf16(ah_c, bl[j], acc[j], 0, 0, 0);
      acc[j] = __builtin_amdgcn_mfma_f32_16x16x32_bf16(al_c, bh[j], acc[j], 0, 0, 0);
    }
    ah_c = ah_n; al_c = al_n;
  }
  int wrow0 = wid * 16;
#pragma unroll
  for (int j = 0; j < 8; ++j) {
    int col = j * 16 + ml;
    float bv = bias[col];
#pragma unroll
    for (int r = 0; r < 4; ++r) {
      int row = wrow0 + krow * 4 + r;
      if (row < M) {
        float v = acc[j][r] + bv;
        if (MODE != 2) v = fmaxf(v, 0.f);
        if (MODE == 0) {
          Ci[(size_t)row * 128 + col] = pack_hl(v);
          H16[(size_t)row * 128 + col] = f_to_f16(v);
        } else if (MODE == 1) {
          size_t o = ((size_t)(row >> 4) * 16 + (col >> 3)) * 128 + (row & 15) * 8 + (col & 7);
          ushort_t hb = f_to_bf16(v);
          Chi[o] = hb;
          Clo[o] = f_to_bf16(v - bf16_to_f(hb));
        } else {
          Cf[(size_t)row * 128 + col] = v;
        }
      }
    }
  }
}

// ---------------------------------------------------------------------------
extern "C" void kernel_launch(void* const* d_in, const int* in_sizes, int n_in,
                              void* d_out, int out_size, void* d_ws, size_t ws_size,
                              hipStream_t stream) {
  const float* x  = (const float*)d_in[0];
  const int*   ei = (const int*)d_in[1];
  const float* Wl[3]  = {(const float*)d_in[2], (const float*)d_in[6], (const float*)d_in[10]};
  const float* asr[3] = {(const float*)d_in[3], (const float*)d_in[7], (const float*)d_in[11]};
  const float* adr[3] = {(const float*)d_in[4], (const float*)d_in[8], (const float*)d_in[12]};
  const float* bl[3]  = {(const float*)d_in[5], (const float*)d_in[9], (const float*)d_in[13]};
  const float* Wp = (const float*)d_in[14];
  const float* bp = (const float*)d_in[15];

  const int N = in_sizes[0] / 128;   // 50000
  const int E = in_sizes[1] / 2;     // 400000
  const int EN = E + N;
  const int Mtiles = (N + 127) / 128;  // 391
  const int Mp = Mtiles * 128;         // 50048
  const int NB = (N + 255) / 256;
  const int NPB = Mp / 16 / 4;         // 782 GEMM blocks

  char* ws = (char*)d_ws;
  size_t off = 0;
  auto carve = [&](size_t bytes) -> void* {
    void* p = ws + off;
    off = (off + bytes + 255) & ~(size_t)255;
    return p;
  };
  ushort_t* Ghi   = (ushort_t*)carve((size_t)Mp * 512 * 2);  // frag layout
  ushort_t* Glo   = (ushort_t*)carve((size_t)Mp * 512 * 2);
  uint_t*   hiA   = (uint_t*)carve((size_t)N * 128 * 4);     // packed hi/lo (al)
  uint_t*   hiB   = (uint_t*)carve((size_t)N * 128 * 4);
  ushort_t* h16   = (ushort_t*)carve((size_t)N * 128 * 2);   // fp16 (agg gather)
  ushort_t* h3hi  = (ushort_t*)carve((size_t)Mp * 128 * 2);  // frag (proj input)
  ushort_t* h3lo  = (ushort_t*)carve((size_t)Mp * 128 * 2);
  ushort_t* wshi  = (ushort_t*)carve((size_t)128 * 512 * 2);
  ushort_t* wslo  = (ushort_t*)carve((size_t)128 * 512 * 2);
  float*    alsrc = (float*)carve((size_t)N * 4 * 4);
  float*    aldst = (float*)carve((size_t)N * 4 * 4);
  float*    Wsb   = (float*)carve(512 * 4);
  float*    Wdb   = (float*)carve(512 * 4);
  int*      rowptr= (int*)carve((size_t)(N + 1) * 4);
  int*      deg   = (int*)carve((size_t)N * 4);
  int*      bsum  = (int*)carve(256 * 4);
  int*      fillc = (int*)carve((size_t)N * 4);
  int*      colbuf= (int*)carve((size_t)EN * 4);
  int*      flag  = (int*)carve(256);

  // ---- CSR build ----
  detect_i64_kernel<<<1, 64, 0, stream>>>(ei, flag);
  hipMemsetAsync(deg, 0, (size_t)N * 4, stream);
  hipMemsetAsync(fillc, 0, (size_t)N * 4, stream);
  int ebl = (EN + 255) / 256;
  deg_kernel<<<ebl, 256, 0, stream>>>(ei, flag, E, N, deg);
  scan_blk_kernel<<<NB, 256, 0, stream>>>(deg, rowptr, bsum, N);
  scan_top_kernel<<<1, 256, 0, stream>>>(bsum, NB);
  scan_add_kernel<<<NB, 256, 0, stream>>>(rowptr, bsum, N);
  fill_kernel<<<ebl, 256, 0, stream>>>(ei, flag, E, N, rowptr, fillc, colbuf);

  // ---- split x into packed + fp16 ----
  const int n_real = N * 128;
  split_x_i_kernel<<<(n_real / 4 + 255) / 256, 256, 0, stream>>>(x, hiA, h16, n_real);

  // ---- 3 GAT layers ----
  uint_t* hin = hiA;
  uint_t* hnext = hiB;
  for (int L = 0; L < 3; ++L) {
    wsd_kernel<<<32, 256, 0, stream>>>(Wl[L], asr[L], adr[L], Wsb, Wdb);
    al_kernel_i<<<(N + 3) / 4, 256, 0, stream>>>(hin, Wsb, Wdb, alsrc, aldst, N);
    agg_G_kernel<<<Mp / 8, 256, 0, stream>>>(h16, alsrc, aldst,
                                             rowptr, colbuf, Ghi, Glo, N);
    split_wstack_frag_kernel<<<256, 256, 0, stream>>>(Wl[L], wshi, wslo);
    if (L < 2) {
      gemm_frag_kernel<512, 0><<<NPB, 256, 0, stream>>>(Ghi, Glo, wshi, wslo,
                                                        hnext, h16, nullptr, nullptr,
                                                        nullptr, N, bl[L]);
      uint_t* t = hin; hin = hnext; hnext = t;
    } else {
      gemm_frag_kernel<512, 1><<<NPB, 256, 0, stream>>>(Ghi, Glo, wshi, wslo,
                                                        nullptr, nullptr, h3hi, h3lo,
                                                        nullptr, N, bl[L]);
    }
  }

  // ---- final projection: out = h3 @ Wp + bp ----
  split_wt_frag_kernel<<<64, 256, 0, stream>>>(Wp, wshi, wslo);
  gemm_frag_kernel<128, 2><<<NPB, 256, 0, stream>>>(h3hi, h3lo, wshi, wslo,
                                                    nullptr, nullptr, nullptr, nullptr,
                                                    (float*)d_out, N, bp);
}

// Round 12
// 420.892 us; speedup vs baseline: 2.0299x; 1.1443x over previous
//
#include <hip/hip_runtime.h>
#include <cstddef>
#include <cstdint>

typedef _Float16 half8 __attribute__((ext_vector_type(8)));
typedef float f32x4 __attribute__((ext_vector_type(4)));
typedef unsigned short ushort_t;
typedef unsigned int uint_t;
typedef ushort_t ushort4v __attribute__((ext_vector_type(4)));
typedef float f32x4v __attribute__((ext_vector_type(4)));

#define INV_LN2 1.4426950408889634f
#define RESCALE_THR 12.0f

__device__ __forceinline__ float bf16_to_f(ushort_t u) {
  union { unsigned int i; float f; } v; v.i = ((unsigned int)u) << 16; return v.f;
}
__device__ __forceinline__ float lo16f(uint_t u) {
  union { uint_t i; float f; } v; v.i = u << 16; return v.f;
}
__device__ __forceinline__ float hi16f(uint_t u) {
  union { uint_t i; float f; } v; v.i = u & 0xffff0000u; return v.f;
}
__device__ __forceinline__ ushort_t f_to_bf16(float f) {
  union { float ff; unsigned int i; } v; v.ff = f;
  unsigned int x = v.i;
  unsigned int lsb = (x >> 16) & 1u;
  x += 0x7fffu + lsb;
  return (ushort_t)(x >> 16);
}
__device__ __forceinline__ uint_t pack_hl(float f) {
  ushort_t hb = f_to_bf16(f);
  ushort_t lb = f_to_bf16(f - bf16_to_f(hb));
  return (uint_t)hb | ((uint_t)lb << 16);
}
__device__ __forceinline__ ushort_t f_to_f16(float f) {
  _Float16 h = (_Float16)f;
  union { _Float16 h; ushort_t u; } v; v.h = h; return v.u;
}
__device__ __forceinline__ float f16_to_f(ushort_t u) {
  union { ushort_t u; _Float16 h; } v; v.u = u; return (float)v.h;
}

// ---------------------------------------------------------------------------
// CSR build
// ---------------------------------------------------------------------------
__global__ __launch_bounds__(64) void detect_i64_kernel(const int* __restrict__ ei,
                                                        int* __restrict__ flag) {
  if (threadIdx.x == 0) {
    int is32 = 0;
    for (int i = 1; i < 1001; i += 2) {
      if (ei[i] != 0) { is32 = 1; break; }
    }
    *flag = is32;
  }
}

__device__ __forceinline__ int load_src(const int* ei, int is32, int E, int e) {
  return is32 ? ei[e] : ei[2 * e];
}
__device__ __forceinline__ int load_dst(const int* ei, int is32, int E, int e) {
  return is32 ? ei[E + e] : ei[2 * (E + e)];
}

__global__ __launch_bounds__(256) void deg_kernel(const int* __restrict__ ei,
                                                  const int* __restrict__ flag,
                                                  int E, int N, int* __restrict__ deg) {
  int e = blockIdx.x * 256 + threadIdx.x;
  if (e >= E + N) return;
  int d = (e < E) ? load_dst(ei, *flag, E, e) : (e - E);
  atomicAdd(&deg[d], 1);
}

__global__ __launch_bounds__(256) void scan_blk_kernel(const int* __restrict__ deg,
                                                       int* __restrict__ rowptr,
                                                       int* __restrict__ bsum, int N) {
  __shared__ int buf[256];
  int b = blockIdx.x, t = threadIdx.x, i = b * 256 + t;
  int v = (i < N) ? deg[i] : 0;
  buf[t] = v;
  __syncthreads();
  for (int off = 1; off < 256; off <<= 1) {
    int add = (t >= off) ? buf[t - off] : 0;
    __syncthreads();
    buf[t] += add;
    __syncthreads();
  }
  if (i < N) rowptr[i + 1] = buf[t];
  if (t == 255) bsum[b] = buf[255];
  if (b == 0 && t == 0) rowptr[0] = 0;
}

__global__ __launch_bounds__(256) void scan_top_kernel(int* __restrict__ bsum, int NB) {
  __shared__ int buf[256];
  int t = threadIdx.x;
  int v = (t < NB) ? bsum[t] : 0;
  buf[t] = v;
  __syncthreads();
  for (int off = 1; off < 256; off <<= 1) {
    int add = (t >= off) ? buf[t - off] : 0;
    __syncthreads();
    buf[t] += add;
    __syncthreads();
  }
  if (t < NB) bsum[t] = buf[t];
}

__global__ __launch_bounds__(256) void scan_add_kernel(int* __restrict__ rowptr,
                                                       const int* __restrict__ bsum, int N) {
  int b = blockIdx.x, t = threadIdx.x, i = b * 256 + t;
  if (b > 0 && i < N) rowptr[i + 1] += bsum[b - 1];
}

__global__ __launch_bounds__(256) void fill_kernel(const int* __restrict__ ei,
                                                   const int* __restrict__ flag,
                                                   int E, int N,
                                                   const int* __restrict__ rowptr,
                                                   int* __restrict__ fillc,
                                                   int* __restrict__ colbuf) {
  int e = blockIdx.x * 256 + threadIdx.x;
  if (e >= E + N) return;
  int s, d;
  if (e < E) { int is32 = *flag; s = load_src(ei, is32, E, e); d = load_dst(ei, is32, E, e); }
  else { s = e - E; d = s; }
  int pos = atomicAdd(&fillc[d], 1);
  colbuf[rowptr[d] + pos] = s;
}

// ---------------------------------------------------------------------------
// prep kernels
// ---------------------------------------------------------------------------
// fp32 -> packed (bf16hi|bf16lo) uint (for al) + fp16 ushort (for agg gather)
__global__ __launch_bounds__(256) void split_x_i_kernel(const float* __restrict__ h,
                                                        uint_t* __restrict__ hi,
                                                        ushort_t* __restrict__ h16,
                                                        int n) {
  int i = (blockIdx.x * 256 + threadIdx.x) * 4;
  if (i >= n) return;
  f32x4v v = *(const f32x4v*)&h[i];
  uint4 o;
  o.x = pack_hl(v[0]); o.y = pack_hl(v[1]); o.z = pack_hl(v[2]); o.w = pack_hl(v[3]);
  *(uint4*)&hi[i] = o;
  ushort4v s;
  s[0] = f_to_f16(v[0]); s[1] = f_to_f16(v[1]);
  s[2] = f_to_f16(v[2]); s[3] = f_to_f16(v[3]);
  *(ushort4v*)&h16[i] = s;
}

// Wp [k=128][col=128] fp32 -> fp16 frag layout
// off = ((col>>4)*16 + (k>>3))*128 + (col&15)*8 + (k&7)
__global__ __launch_bounds__(256) void split_wt_frag_kernel(const float* __restrict__ W,
                                                            ushort_t* __restrict__ Wf) {
  int t = blockIdx.x * 256 + threadIdx.x;   // 16384
  int blk = t >> 7, rem = t & 127;
  int c16 = blk >> 4, k8 = blk & 15;
  int cl = rem >> 3, kl = rem & 7;
  int col = c16 * 16 + cl, k = k8 * 8 + kl;
  Wf[t] = f_to_f16(W[(size_t)k * 128 + col]);
}

// W [128][512] -> Wstack fp16 frag layout (K=512), val = 0.25*W[f][h*128+col]
__global__ __launch_bounds__(256) void split_wstack_frag_kernel(const float* __restrict__ W,
                                                                ushort_t* __restrict__ Wf) {
  int t = blockIdx.x * 256 + threadIdx.x;   // 65536
  int c16 = t >> 13;
  int r = t & 8191;
  int k8 = r >> 7;
  int rem = r & 127;
  int rl = rem >> 3, kl = rem & 7;
  int col = c16 * 16 + rl;
  int k = k8 * 8 + kl;
  int h = k >> 7, f = k & 127;
  Wf[t] = f_to_f16(0.25f * W[(size_t)f * 512 + h * 128 + col]);
}

// Ws[h*128+f] = (1/ln2) * sum_d W[f, h*128+d] * a_src[h, d]
__global__ __launch_bounds__(256) void wsd_kernel(const float* __restrict__ W,
                                                  const float* __restrict__ a_src,
                                                  const float* __restrict__ a_dst,
                                                  float* __restrict__ Ws,
                                                  float* __restrict__ Wd) {
  int wave = threadIdx.x >> 6, lane = threadIdx.x & 63;
  int f = blockIdx.x * 4 + wave;          // grid = 32 -> f in [0,128)
  int base = lane * 8;
  float4 w0 = *(const float4*)&W[(size_t)f * 512 + base];
  float4 w1 = *(const float4*)&W[(size_t)f * 512 + base + 4];
  float4 s0 = *(const float4*)&a_src[base];
  float4 s1 = *(const float4*)&a_src[base + 4];
  float4 d0 = *(const float4*)&a_dst[base];
  float4 d1 = *(const float4*)&a_dst[base + 4];
  float ps = w0.x*s0.x + w0.y*s0.y + w0.z*s0.z + w0.w*s0.w
           + w1.x*s1.x + w1.y*s1.y + w1.z*s1.z + w1.w*s1.w;
  float pd = w0.x*d0.x + w0.y*d0.y + w0.z*d0.z + w0.w*d0.w
           + w1.x*d1.x + w1.y*d1.y + w1.z*d1.z + w1.w*d1.w;
#pragma unroll
  for (int off = 1; off <= 8; off <<= 1) {
    ps += __shfl_xor(ps, off);
    pd += __shfl_xor(pd, off);
  }
  if ((lane & 15) == 0) {
    int h = lane >> 4;
    Ws[h * 128 + f] = ps * INV_LN2;
    Wd[h * 128 + f] = pd * INV_LN2;
  }
}

// al_src/al_dst [N,4] from packed hi/lo h (full precision). One wave per node.
__global__ __launch_bounds__(256) void al_kernel_i(const uint_t* __restrict__ hint,
                                                   const float* __restrict__ Ws,
                                                   const float* __restrict__ Wd,
                                                   float* __restrict__ al_src,
                                                   float* __restrict__ al_dst, int N) {
  __shared__ float sWs[512], sWd[512];
  int t = threadIdx.x;
  sWs[t] = Ws[t]; sWs[t + 256] = Ws[t + 256];
  sWd[t] = Wd[t]; sWd[t + 256] = Wd[t + 256];
  __syncthreads();
  int wave = t >> 6, lane = t & 63;
  int n = blockIdx.x * 4 + wave;
  if (n >= N) return;
  uint2 uu = *(const uint2*)&hint[(size_t)n * 128 + lane * 2];
  float v0 = lo16f(uu.x) + hi16f(uu.x);
  float v1 = lo16f(uu.y) + hi16f(uu.y);
  float p[8];
#pragma unroll
  for (int hh = 0; hh < 4; ++hh) {
    p[hh]     = v0 * sWs[hh * 128 + 2 * lane] + v1 * sWs[hh * 128 + 2 * lane + 1];
    p[4 + hh] = v0 * sWd[hh * 128 + 2 * lane] + v1 * sWd[hh * 128 + 2 * lane + 1];
  }
#pragma unroll
  for (int off = 32; off; off >>= 1)
#pragma unroll
    for (int i = 0; i < 8; ++i) p[i] += __shfl_xor(p[i], off);
  if (lane == 0) {
#pragma unroll
    for (int hh = 0; hh < 4; ++hh) {
      al_src[n * 4 + hh] = p[hh];
      al_dst[n * 4 + hh] = p[4 + hh];
    }
  }
}

// ---------------------------------------------------------------------------
// aggregation: 2 nodes per wave (32-lane halves); fp16 value gather (8 B/lane);
// exp2-domain online softmax with deferred rescale; 2-deep pipelined gathers;
// fp16 frag-layout output (single array).
// ---------------------------------------------------------------------------
__global__ __launch_bounds__(256) void agg_G_kernel(const ushort_t* __restrict__ h16,
                                                    const float* __restrict__ al_src,
                                                    const float* __restrict__ al_dst,
                                                    const int* __restrict__ rowptr,
                                                    const int* __restrict__ colbuf,
                                                    ushort_t* __restrict__ Gf, int N) {
  int wave = threadIdx.x >> 6, lane = threadIdx.x & 63;
  int fl = lane & 31;
  int n = blockIdx.x * 8 + wave * 2 + (lane >> 5);
  bool alive = n < N;
  int beg = 0, d = 0;
  float4 ald = make_float4(0.f, 0.f, 0.f, 0.f);
  if (alive) {
    beg = rowptr[n];
    d = rowptr[n + 1] - beg;
    ald = *(const float4*)&al_dst[(size_t)n * 4];
  }
  int dmax = max(d, __shfl_xor(d, 32));
  int dm1 = max(d - 1, 0);
  float m0 = -1e30f, m1 = -1e30f, m2 = -1e30f, m3 = -1e30f;
  float t0 = -1e30f, t1 = -1e30f, t2 = -1e30f, t3 = -1e30f;
  float ss0 = 0.f, ss1 = 0.f, ss2 = 0.f, ss3 = 0.f;
  float a00 = 0.f, a01 = 0.f, a02 = 0.f, a03 = 0.f;
  float a10 = 0.f, a11 = 0.f, a12 = 0.f, a13 = 0.f;
  float a20 = 0.f, a21 = 0.f, a22 = 0.f, a23 = 0.f;
  float a30 = 0.f, a31 = 0.f, a32 = 0.f, a33 = 0.f;

  if (dmax > 0) {
    int s0i = colbuf[beg];
    float4 as_c = *(const float4*)&al_src[(size_t)s0i * 4];
    ushort4v hv_c = *(const ushort4v*)&h16[(size_t)s0i * 128 + fl * 4];
    int s_n = colbuf[beg + min(1, dm1)];
    for (int it = 0; it < dmax; ++it) {
      float4 as_n = *(const float4*)&al_src[(size_t)s_n * 4];
      ushort4v hv_n = *(const ushort4v*)&h16[(size_t)s_n * 128 + fl * 4];
      int s_n2 = colbuf[beg + min(it + 2, dm1)];

      float e0 = as_c.x + ald.x; e0 = fmaxf(e0, 0.2f * e0);
      float e1 = as_c.y + ald.y; e1 = fmaxf(e1, 0.2f * e1);
      float e2 = as_c.z + ald.z; e2 = fmaxf(e2, 0.2f * e2);
      float e3 = as_c.w + ald.w; e3 = fmaxf(e3, 0.2f * e3);
      bool need = (e0 > t0) || (e1 > t1) || (e2 > t2) || (e3 > t3);
      if (__any(need)) {
        float nm, f;
        nm = fmaxf(m0, e0); f = exp2f(m0 - nm); m0 = nm; t0 = nm + RESCALE_THR;
        ss0 *= f; a00 *= f; a01 *= f; a02 *= f; a03 *= f;
        nm = fmaxf(m1, e1); f = exp2f(m1 - nm); m1 = nm; t1 = nm + RESCALE_THR;
        ss1 *= f; a10 *= f; a11 *= f; a12 *= f; a13 *= f;
        nm = fmaxf(m2, e2); f = exp2f(m2 - nm); m2 = nm; t2 = nm + RESCALE_THR;
        ss2 *= f; a20 *= f; a21 *= f; a22 *= f; a23 *= f;
        nm = fmaxf(m3, e3); f = exp2f(m3 - nm); m3 = nm; t3 = nm + RESCALE_THR;
        ss3 *= f; a30 *= f; a31 *= f; a32 *= f; a33 *= f;
      }
      float w0 = exp2f(e0 - m0);
      float w1 = exp2f(e1 - m1);
      float w2 = exp2f(e2 - m2);
      float w3 = exp2f(e3 - m3);
      bool valid = it < d;
      w0 = valid ? w0 : 0.f;
      w1 = valid ? w1 : 0.f;
      w2 = valid ? w2 : 0.f;
      w3 = valid ? w3 : 0.f;
      ss0 += w0; ss1 += w1; ss2 += w2; ss3 += w3;
      float v0 = f16_to_f(hv_c[0]);
      float v1 = f16_to_f(hv_c[1]);
      float v2 = f16_to_f(hv_c[2]);
      float v3 = f16_to_f(hv_c[3]);
      a00 += w0 * v0; a01 += w0 * v1; a02 += w0 * v2; a03 += w0 * v3;
      a10 += w1 * v0; a11 += w1 * v1; a12 += w1 * v2; a13 += w1 * v3;
      a20 += w2 * v0; a21 += w2 * v1; a22 += w2 * v2; a23 += w2 * v3;
      a30 += w3 * v0; a31 += w3 * v1; a32 += w3 * v2; a33 += w3 * v3;
      as_c = as_n; hv_c = hv_n; s_n = s_n2;
    }
  }
  if (!alive) return;
  float g[4][4];
  float inv;
  inv = 1.f / (ss0 + 1e-16f); g[0][0] = a00 * inv; g[0][1] = a01 * inv; g[0][2] = a02 * inv; g[0][3] = a03 * inv;
  inv = 1.f / (ss1 + 1e-16f); g[1][0] = a10 * inv; g[1][1] = a11 * inv; g[1][2] = a12 * inv; g[1][3] = a13 * inv;
  inv = 1.f / (ss2 + 1e-16f); g[2][0] = a20 * inv; g[2][1] = a21 * inv; g[2][2] = a22 * inv; g[2][3] = a23 * inv;
  inv = 1.f / (ss3 + 1e-16f); g[3][0] = a30 * inv; g[3][1] = a31 * inv; g[3][2] = a32 * inv; g[3][3] = a33 * inv;
#pragma unroll
  for (int h = 0; h < 4; ++h) {
    ushort_t q0 = f_to_f16(g[h][0]), q1 = f_to_f16(g[h][1]);
    ushort_t q2 = f_to_f16(g[h][2]), q3 = f_to_f16(g[h][3]);
    size_t o = ((size_t)(n >> 4) * 64 + h * 16 + (fl >> 1)) * 128 + (n & 15) * 8 + (fl & 1) * 4;
    *(uint2*)&Gf[o] = make_uint2((uint_t)q0 | ((uint_t)q1 << 16),
                                 (uint_t)q2 | ((uint_t)q3 << 16));
  }
}

// ---------------------------------------------------------------------------
// Barrier-free fp16 MFMA GEMM from fragment-layout inputs. Compile-time K/MODE.
// 4 waves/block, 16 rows/wave, single MFMA pass (fp32 accumulate).
// MODE 0: packed-uint + fp16 row out (relu); 1: fp16 frag out (relu);
// MODE 2: fp32 row out (no relu).
// ---------------------------------------------------------------------------
template <int K, int MODE>
__global__ __launch_bounds__(256) void gemm_frag_kernel(
    const ushort_t* __restrict__ Af, const ushort_t* __restrict__ Bf,
    uint_t* __restrict__ Ci, ushort_t* __restrict__ H16,
    ushort_t* __restrict__ Cf16, float* __restrict__ Cf,
    int M, const float* __restrict__ bias) {
  constexpr int KT = K >> 5;
  constexpr int PS = 16 * K;          // panel stride (ushorts)
  int lane = threadIdx.x & 63;
  int wid = blockIdx.x * 4 + (threadIdx.x >> 6);
  int krow = lane >> 4, ml = lane & 15;
  int lb = krow * 128 + ml * 8;
  size_t abase = (size_t)wid * PS + lb;
  f32x4 acc[8] = {};
  half8 a_c = *(const half8*)&Af[abase];
#pragma unroll
  for (int kt = 0; kt < KT; ++kt) {
    half8 a_n = a_c;
    if (kt + 1 < KT) a_n = *(const half8*)&Af[abase + (kt + 1) * 512];
    half8 b[8];
#pragma unroll
    for (int j = 0; j < 8; ++j)
      b[j] = *(const half8*)&Bf[j * PS + kt * 512 + lb];
#pragma unroll
    for (int j = 0; j < 8; ++j)
      acc[j] = __builtin_amdgcn_mfma_f32_16x16x32_f16(a_c, b[j], acc[j], 0, 0, 0);
    a_c = a_n;
  }
  int wrow0 = wid * 16;
#pragma unroll
  for (int j = 0; j < 8; ++j) {
    int col = j * 16 + ml;
    float bv = bias[col];
#pragma unroll
    for (int r = 0; r < 4; ++r) {
      int row = wrow0 + krow * 4 + r;
      if (row < M) {
        float v = acc[j][r] + bv;
        if (MODE != 2) v = fmaxf(v, 0.f);
        if (MODE == 0) {
          Ci[(size_t)row * 128 + col] = pack_hl(v);
          H16[(size_t)row * 128 + col] = f_to_f16(v);
        } else if (MODE == 1) {
          size_t o = ((size_t)(row >> 4) * 16 + (col >> 3)) * 128 + (row & 15) * 8 + (col & 7);
          Cf16[o] = f_to_f16(v);
        } else {
          Cf[(size_t)row * 128 + col] = v;
        }
      }
    }
  }
}

// ---------------------------------------------------------------------------
extern "C" void kernel_launch(void* const* d_in, const int* in_sizes, int n_in,
                              void* d_out, int out_size, void* d_ws, size_t ws_size,
                              hipStream_t stream) {
  const float* x  = (const float*)d_in[0];
  const int*   ei = (const int*)d_in[1];
  const float* Wl[3]  = {(const float*)d_in[2], (const float*)d_in[6], (const float*)d_in[10]};
  const float* asr[3] = {(const float*)d_in[3], (const float*)d_in[7], (const float*)d_in[11]};
  const float* adr[3] = {(const float*)d_in[4], (const float*)d_in[8], (const float*)d_in[12]};
  const float* bl[3]  = {(const float*)d_in[5], (const float*)d_in[9], (const float*)d_in[13]};
  const float* Wp = (const float*)d_in[14];
  const float* bp = (const float*)d_in[15];

  const int N = in_sizes[0] / 128;   // 50000
  const int E = in_sizes[1] / 2;     // 400000
  const int EN = E + N;
  const int Mtiles = (N + 127) / 128;  // 391
  const int Mp = Mtiles * 128;         // 50048
  const int NB = (N + 255) / 256;
  const int NPB = Mp / 16 / 4;         // 782 GEMM blocks

  char* ws = (char*)d_ws;
  size_t off = 0;
  auto carve = [&](size_t bytes) -> void* {
    void* p = ws + off;
    off = (off + bytes + 255) & ~(size_t)255;
    return p;
  };
  ushort_t* Gf    = (ushort_t*)carve((size_t)Mp * 512 * 2);  // fp16 frag layout, 51.2 MB
  uint_t*   hiA   = (uint_t*)carve((size_t)N * 128 * 4);     // packed hi/lo (al)
  uint_t*   hiB   = (uint_t*)carve((size_t)N * 128 * 4);
  ushort_t* h16   = (ushort_t*)carve((size_t)N * 128 * 2);   // fp16 (agg gather)
  ushort_t* h3f   = (ushort_t*)carve((size_t)Mp * 128 * 2);  // fp16 frag (proj input)
  ushort_t* wsf   = (ushort_t*)carve((size_t)128 * 512 * 2); // fp16 frag Wstack / Wp
  float*    alsrc = (float*)carve((size_t)N * 4 * 4);
  float*    aldst = (float*)carve((size_t)N * 4 * 4);
  float*    Wsb   = (float*)carve(512 * 4);
  float*    Wdb   = (float*)carve(512 * 4);
  int*      rowptr= (int*)carve((size_t)(N + 1) * 4);
  int*      deg   = (int*)carve((size_t)N * 4);
  int*      bsum  = (int*)carve(256 * 4);
  int*      fillc = (int*)carve((size_t)N * 4);
  int*      colbuf= (int*)carve((size_t)EN * 4);
  int*      flag  = (int*)carve(256);

  // ---- CSR build ----
  detect_i64_kernel<<<1, 64, 0, stream>>>(ei, flag);
  hipMemsetAsync(deg, 0, (size_t)N * 4, stream);
  hipMemsetAsync(fillc, 0, (size_t)N * 4, stream);
  int ebl = (EN + 255) / 256;
  deg_kernel<<<ebl, 256, 0, stream>>>(ei, flag, E, N, deg);
  scan_blk_kernel<<<NB, 256, 0, stream>>>(deg, rowptr, bsum, N);
  scan_top_kernel<<<1, 256, 0, stream>>>(bsum, NB);
  scan_add_kernel<<<NB, 256, 0, stream>>>(rowptr, bsum, N);
  fill_kernel<<<ebl, 256, 0, stream>>>(ei, flag, E, N, rowptr, fillc, colbuf);

  // ---- split x into packed + fp16 ----
  const int n_real = N * 128;
  split_x_i_kernel<<<(n_real / 4 + 255) / 256, 256, 0, stream>>>(x, hiA, h16, n_real);

  // ---- 3 GAT layers ----
  uint_t* hin = hiA;
  uint_t* hnext = hiB;
  for (int L = 0; L < 3; ++L) {
    wsd_kernel<<<32, 256, 0, stream>>>(Wl[L], asr[L], adr[L], Wsb, Wdb);
    al_kernel_i<<<(N + 3) / 4, 256, 0, stream>>>(hin, Wsb, Wdb, alsrc, aldst, N);
    agg_G_kernel<<<Mp / 8, 256, 0, stream>>>(h16, alsrc, aldst,
                                             rowptr, colbuf, Gf, N);
    split_wstack_frag_kernel<<<256, 256, 0, stream>>>(Wl[L], wsf);
    if (L < 2) {
      gemm_frag_kernel<512, 0><<<NPB, 256, 0, stream>>>(Gf, wsf,
                                                        hnext, h16, nullptr, nullptr,
                                                        N, bl[L]);
      uint_t* t = hin; hin = hnext; hnext = t;
    } else {
      gemm_frag_kernel<512, 1><<<NPB, 256, 0, stream>>>(Gf, wsf,
                                                        nullptr, nullptr, h3f, nullptr,
                                                        N, bl[L]);
    }
  }

  // ---- final projection: out = h3 @ Wp + bp ----
  split_wt_frag_kernel<<<64, 256, 0, stream>>>(Wp, wsf);
  gemm_frag_kernel<128, 2><<<NPB, 256, 0, stream>>>(h3f, wsf,
                                                    nullptr, nullptr, nullptr, (float*)d_out,
                                                    N, bp);
}